// Round 9
// baseline (197.199 us; speedup 1.0000x reference)
//
#include <hip/hip_runtime.h>
#include <stdint.h>

#define N_TOK 4096
#define DIM   512
#define BATCH 4
#define BN    (BATCH * N_TOK)
#define JSPLIT 8
#define IPW   32                      // i-rows per wave (A resident in regs)
#define IPB   128                     // i-rows per block (4 waves)
#define NG    (N_TOK / JSPLIT / 16)   // 32 j-groups of 16 per slice

typedef __attribute__((ext_vector_type(4))) float f32x4;

__device__ __forceinline__ float sumsq8(uint lo, uint hi) {
    float s = 0.f, f;
    f = __builtin_amdgcn_cvt_f32_fp8((int)lo, 0); s = fmaf(f, f, s);
    f = __builtin_amdgcn_cvt_f32_fp8((int)lo, 1); s = fmaf(f, f, s);
    f = __builtin_amdgcn_cvt_f32_fp8((int)lo, 2); s = fmaf(f, f, s);
    f = __builtin_amdgcn_cvt_f32_fp8((int)lo, 3); s = fmaf(f, f, s);
    f = __builtin_amdgcn_cvt_f32_fp8((int)hi, 0); s = fmaf(f, f, s);
    f = __builtin_amdgcn_cvt_f32_fp8((int)hi, 1); s = fmaf(f, f, s);
    f = __builtin_amdgcn_cvt_f32_fp8((int)hi, 2); s = fmaf(f, f, s);
    f = __builtin_amdgcn_cvt_f32_fp8((int)hi, 3); s = fmaf(f, f, s);
    return s;
}

// ---------- prep: fp8 convert -> fb (row-major, A-side) + fbT (B-operand-transposed)
//            + per-row sumsq of QUANTIZED values.
__global__ __launch_bounds__(256) void prep_kernel(
    const float* __restrict__ feat, uint8_t* __restrict__ fb,
    uint8_t* __restrict__ fbT, float* __restrict__ sq)
{
    __shared__ __align__(8) uint2 lt[1024];        // [chunk 0..63][row16 0..15], swizzled
    const int t = threadIdx.x;
    const int row16 = t >> 4, seg = t & 15;
    const size_t grp = blockIdx.x;
    const size_t row = grp * 16 + row16;

    const float4* src = (const float4*)(feat + row * DIM + seg * 32);
    uint32_t wd[8];
    float s = 0.f;
#pragma unroll
    for (int i = 0; i < 4; ++i) {
        float4 a = src[2 * i], b = src[2 * i + 1];
        uint lo = (uint)__builtin_amdgcn_cvt_pk_fp8_f32(a.x, a.y, 0, false);
        lo      = (uint)__builtin_amdgcn_cvt_pk_fp8_f32(a.z, a.w, (int)lo, true);
        uint hi = (uint)__builtin_amdgcn_cvt_pk_fp8_f32(b.x, b.y, 0, false);
        hi      = (uint)__builtin_amdgcn_cvt_pk_fp8_f32(b.z, b.w, (int)hi, true);
        wd[2 * i] = lo; wd[2 * i + 1] = hi;
        s += sumsq8(lo, hi);
    }

    uint4* dst = (uint4*)(fb + row * DIM + seg * 32);
    uint4 o0; o0.x = wd[0]; o0.y = wd[1]; o0.z = wd[2]; o0.w = wd[3];
    uint4 o1; o1.x = wd[4]; o1.y = wd[5]; o1.z = wd[6]; o1.w = wd[7];
    dst[0] = o0; dst[1] = o1;

#pragma unroll
    for (int i = 0; i < 4; ++i) {
        int c = seg * 4 + i;
        uint2 d; d.x = wd[2 * i]; d.y = wd[2 * i + 1];
        lt[c * 16 + ((row16 + c) & 15)] = d;
    }

#pragma unroll
    for (int m = 1; m < 16; m <<= 1) s += __shfl_xor(s, m);
    if (seg == 0) sq[row] = s;

    __syncthreads();
    uint2* ot = (uint2*)(fbT + grp * 8192);
#pragma unroll
    for (int i = 0; i < 4; ++i) {
        int p = t + i * 256;                       // p = chunk*16 + r16, coalesced out
        int c = p >> 4, r = p & 15;
        ot[p] = lt[c * 16 + ((r + c) & 15)];
    }
}

// ---------- entropy: register-resident A (32 i-rows/wave), register B from fbT ----------
// grid (N/128, B, 8) = 1024 blocks (4/CU), 256 thr = 4 independent waves, NO LDS/barriers.
// 2 strips => afrag 64 regs; total wave footprint ~125 regs => 4 waves/SIMD (vs 2 at
// the R8 64-row design whose true footprint was ~240: VGPR_Count hides the AGPR side).
// 4 accumulator chains (even/odd kc x 2 strips) keep dependent-MFMA latency covered.
__global__ __launch_bounds__(256, 2) void entropy_kernel(
    const uint8_t* __restrict__ fb, const uint8_t* __restrict__ fbT,
    const float* __restrict__ sq, const float* __restrict__ temp,
    float* __restrict__ Sp, float* __restrict__ Tp)
{
    const int t    = threadIdx.x;
    const int w    = t >> 6;
    const int lane = t & 63;
    const int q    = lane >> 4;
    const int c16  = lane & 15;

    const int batch = blockIdx.y;
    const int jh    = blockIdx.z;
    const int iw    = blockIdx.x * IPB + w * IPW;
    const size_t rowbase = (size_t)batch * N_TOK;

    const float tau    = temp[0];
    const float inv2t2 = 0.5f / (tau * tau);
    const float cg     = 1.0f / (tau * tau);

    // A fragments: 2 strips x 16 k-chunks x 8B = 64 regs
    long afrag[2][16];
#pragma unroll
    for (int s = 0; s < 2; ++s) {
        const long* ap = (const long*)(fb + (rowbase + iw + s * 16 + c16) * DIM);
#pragma unroll
        for (int kc = 0; kc < 16; ++kc) afrag[s][kc] = ap[kc * 4 + q];
    }
    float pi[2][4];
#pragma unroll
    for (int s = 0; s < 2; ++s)
#pragma unroll
        for (int r = 0; r < 4; ++r)
            pi[s][r] = -sq[rowbase + iw + s * 16 + q * 4 + r] * inv2t2;

    float S[2][4], T[2][4];
#pragma unroll
    for (int s = 0; s < 2; ++s)
#pragma unroll
        for (int r = 0; r < 4; ++r) { S[s][r] = 0.f; T[s][r] = 0.f; }

    // per-lane B pointer into fbT: group-major, [kc][q][r16] inside each 8KB group
    const long*  bp  = (const long*)fbT
                     + ((size_t)batch * (N_TOK / 16) + (size_t)jh * NG) * 1024
                     + q * 16 + c16;
    const float* sqj = sq + rowbase + jh * (N_TOK / JSPLIT) + c16;

    for (int g = 0; g < NG; ++g) {
        float pj = -sqj[g * 16] * inv2t2;
        const long* bg = bp + (size_t)g * 1024;
        // 4 independent chains: strip x (even/odd kc)
        f32x4 aE[2] = {{0,0,0,0},{0,0,0,0}}, aO[2] = {{0,0,0,0},{0,0,0,0}};
#pragma unroll
        for (int kc = 0; kc < 16; kc += 2) {
            long b0 = bg[kc * 64];                 // coalesced 512B wave loads
            long b1 = bg[(kc + 1) * 64];
            aE[0] = __builtin_amdgcn_mfma_f32_16x16x32_fp8_fp8(afrag[0][kc],     b0, aE[0], 0, 0, 0);
            aE[1] = __builtin_amdgcn_mfma_f32_16x16x32_fp8_fp8(afrag[1][kc],     b0, aE[1], 0, 0, 0);
            aO[0] = __builtin_amdgcn_mfma_f32_16x16x32_fp8_fp8(afrag[0][kc + 1], b1, aO[0], 0, 0, 0);
            aO[1] = __builtin_amdgcn_mfma_f32_16x16x32_fp8_fp8(afrag[1][kc + 1], b1, aO[1], 0, 0, 0);
        }
        float m = -1e30f;
#pragma unroll
        for (int s = 0; s < 2; ++s)
#pragma unroll
            for (int r = 0; r < 4; ++r) {          // e in-place over aE (acc dead after)
                aE[s][r] = fmaf(aE[s][r] + aO[s][r], cg, pi[s][r] + pj);
                m = fmaxf(m, aE[s][r]);
            }
        if (m > -110.0f) {                         // rare: only diagonal-adjacent groups
#pragma unroll
            for (int s = 0; s < 2; ++s)
#pragma unroll
                for (int r = 0; r < 4; ++r) {
                    float ee = fminf(aE[s][r], 0.f);
                    float k  = __expf(ee);
                    S[s][r] += k;
                    T[s][r]  = fmaf(k, ee, T[s][r]);
                }
        }
    }

    // reduce over the 16 j-columns (c16 lanes)
#pragma unroll
    for (int m = 1; m < 16; m <<= 1)
#pragma unroll
        for (int s = 0; s < 2; ++s)
#pragma unroll
            for (int r = 0; r < 4; ++r) {
                S[s][r] += __shfl_xor(S[s][r], m);
                T[s][r] += __shfl_xor(T[s][r], m);
            }

    if (c16 == 0) {
#pragma unroll
        for (int s = 0; s < 2; ++s)
#pragma unroll
            for (int r = 0; r < 4; ++r) {
                size_t idx = (size_t)jh * BN + rowbase + iw + s * 16 + q * 4 + r;
                Sp[idx] = S[s][r];
                Tp[idx] = T[s][r];
            }
    }
}

// ---------- finalize: combine partials, entropy -> sigmoid -> scale features ----------
__global__ __launch_bounds__(256) void finalize_kernel(
    const float* __restrict__ feat, const float* __restrict__ Sp,
    const float* __restrict__ Tp, const float* __restrict__ tgt,
    const float* __restrict__ temp, float* __restrict__ out)
{
    int row  = (blockIdx.x << 2) + (threadIdx.x >> 6);   // global row 0..BN-1
    int lane = threadIdx.x & 63;
    float S = 0.0f, T = 0.0f;
#pragma unroll
    for (int j = 0; j < JSPLIT; ++j) {
        S += Sp[(size_t)j * BN + row];
        T += Tp[(size_t)j * BN + row];
    }
    float tau = temp[0];
    float E  = __logf(S) - T / S;                  // entropy (sans +1e-6, bias<4e-3)
    float cs = 1.0f / (1.0f + __expf((E - tgt[0]) / tau));

    const float4* F4 = (const float4*)(feat + (size_t)row * DIM);
    float4*       O4 = (float4*)(out + (size_t)row * DIM);
    float4 v0 = F4[lane], v1 = F4[lane + 64];
    v0.x *= cs; v0.y *= cs; v0.z *= cs; v0.w *= cs;
    v1.x *= cs; v1.y *= cs; v1.z *= cs; v1.w *= cs;
    O4[lane] = v0; O4[lane + 64] = v1;
    if (lane == 0) out[(size_t)BN * DIM + row] = cs;
}

extern "C" void kernel_launch(void* const* d_in, const int* in_sizes, int n_in,
                              void* d_out, int out_size, void* d_ws, size_t ws_size,
                              hipStream_t stream) {
    const float* feat = (const float*)d_in[0];
    const float* tgt  = (const float*)d_in[7];   // target_entropy
    const float* temp = (const float*)d_in[8];   // temperature
    float* out = (float*)d_out;

    char* ws = (char*)d_ws;
    uint8_t* fb  = (uint8_t*)ws;                               // fp8 row-major, 8.4MB
    uint8_t* fbT = fb + (size_t)BN * DIM;                      // fp8 B-transposed, 8.4MB
    float*   sq  = (float*)(fbT + (size_t)BN * DIM);           // quantized row sumsq
    float*   Sp  = sq + BN;                                    // partial S, JSPLIT slices
    float*   Tp  = Sp + (size_t)JSPLIT * BN;                   // partial T, JSPLIT slices

    prep_kernel<<<dim3(BN / 16), dim3(256), 0, stream>>>(feat, fb, fbT, sq);
    entropy_kernel<<<dim3(N_TOK / IPB, BATCH, JSPLIT), dim3(256), 0, stream>>>(fb, fbT, sq, temp, Sp, Tp);
    finalize_kernel<<<dim3(BN / 4), dim3(256), 0, stream>>>(feat, Sp, Tp, tgt, temp, out);
}

// Round 10
// 168.296 us; speedup vs baseline: 1.1717x; 1.1717x over previous
//
#include <hip/hip_runtime.h>
#include <stdint.h>

#define N_TOK 4096
#define DIM   512
#define BATCH 4
#define BN    (BATCH * N_TOK)
#define JSPLIT 8
#define IPW   64                      // i-rows per wave (A resident in regs)
#define IPB   256                     // i-rows per block (4 waves)
#define NG    (N_TOK / JSPLIT / 16)   // 32 j-groups of 16 per slice

typedef __attribute__((ext_vector_type(4))) float f32x4;

__device__ __forceinline__ float sumsq8(uint lo, uint hi) {
    float s = 0.f, f;
    f = __builtin_amdgcn_cvt_f32_fp8((int)lo, 0); s = fmaf(f, f, s);
    f = __builtin_amdgcn_cvt_f32_fp8((int)lo, 1); s = fmaf(f, f, s);
    f = __builtin_amdgcn_cvt_f32_fp8((int)lo, 2); s = fmaf(f, f, s);
    f = __builtin_amdgcn_cvt_f32_fp8((int)lo, 3); s = fmaf(f, f, s);
    f = __builtin_amdgcn_cvt_f32_fp8((int)hi, 0); s = fmaf(f, f, s);
    f = __builtin_amdgcn_cvt_f32_fp8((int)hi, 1); s = fmaf(f, f, s);
    f = __builtin_amdgcn_cvt_f32_fp8((int)hi, 2); s = fmaf(f, f, s);
    f = __builtin_amdgcn_cvt_f32_fp8((int)hi, 3); s = fmaf(f, f, s);
    return s;
}

// ---------- prep: fp8 convert -> fb (row-major) + fbT (B-operand, 16B-load layout)
//            + per-row sumsq of QUANTIZED values.
// fbT per 16-row group (8KB): long index p = kp*128 + q*32 + r16*2 + half, so a lane's
// 16B load at (kp, lane=(q,c16)) yields the kc=2kp and kc=2kp+1 B-fragments adjacent.
__global__ __launch_bounds__(256) void prep_kernel(
    const float* __restrict__ feat, uint8_t* __restrict__ fb,
    uint8_t* __restrict__ fbT, float* __restrict__ sq)
{
    __shared__ __align__(16) long lt[1024];        // [chunk c 0..63][row16], swizzled
    const int t = threadIdx.x;
    const int row16 = t >> 4, seg = t & 15;
    const size_t grp = blockIdx.x;
    const size_t row = grp * 16 + row16;

    const float4* src = (const float4*)(feat + row * DIM + seg * 32);
    uint32_t wd[8];
    float s = 0.f;
#pragma unroll
    for (int i = 0; i < 4; ++i) {
        float4 a = src[2 * i], b = src[2 * i + 1];
        uint lo = (uint)__builtin_amdgcn_cvt_pk_fp8_f32(a.x, a.y, 0, false);
        lo      = (uint)__builtin_amdgcn_cvt_pk_fp8_f32(a.z, a.w, (int)lo, true);
        uint hi = (uint)__builtin_amdgcn_cvt_pk_fp8_f32(b.x, b.y, 0, false);
        hi      = (uint)__builtin_amdgcn_cvt_pk_fp8_f32(b.z, b.w, (int)hi, true);
        wd[2 * i] = lo; wd[2 * i + 1] = hi;
        s += sumsq8(lo, hi);
    }

    uint4* dst = (uint4*)(fb + row * DIM + seg * 32);
    uint4 o0; o0.x = wd[0]; o0.y = wd[1]; o0.z = wd[2]; o0.w = wd[3];
    uint4 o1; o1.x = wd[4]; o1.y = wd[5]; o1.z = wd[6]; o1.w = wd[7];
    dst[0] = o0; dst[1] = o1;

#pragma unroll
    for (int i = 0; i < 4; ++i) {
        int c = seg * 4 + i;                       // 8B chunk of this row
        long d = ((long)(unsigned)wd[2 * i + 1] << 32) | (unsigned)wd[2 * i];
        lt[c * 16 + ((row16 + c) & 15)] = d;
    }

#pragma unroll
    for (int m = 1; m < 16; m <<= 1) s += __shfl_xor(s, m);
    if (seg == 0) sq[row] = s;

    __syncthreads();
    long* ot = (long*)(fbT + grp * 8192);
#pragma unroll
    for (int i = 0; i < 4; ++i) {
        int p    = t + i * 256;                    // output long index, coalesced
        int kp   = p >> 7;
        int q    = (p >> 5) & 3;
        int r    = (p >> 1) & 15;
        int half = p & 1;
        int c    = (((kp << 1) | half) << 2) | q;  // source chunk
        ot[p] = lt[c * 16 + ((r + c) & 15)];
    }
}

// ---------- entropy: register-resident A (64 i-rows/wave), register B from fbT ----------
// Flat 512-block grid (2/CU), XCD-swizzled: combo = flat&31 (batch*8+jh) => dispatch
// round-robin puts all 16 i-blocks of a combo on XCD jh => per-XCD hot fbT = 4x256KB
// = 1MB, L2-resident => B-load latency ~200cyc, covered by the 64-MFMA burst.
// 8 x 16B B-loads per group (2 kc each). No LDS, no barriers in hot loop.
__global__ __launch_bounds__(256, 2) void entropy_kernel(
    const uint8_t* __restrict__ fb, const uint8_t* __restrict__ fbT,
    const float* __restrict__ sq, const float* __restrict__ temp,
    float* __restrict__ Sp, float* __restrict__ Tp)
{
    const int t    = threadIdx.x;
    const int w    = t >> 6;
    const int lane = t & 63;
    const int q    = lane >> 4;
    const int c16  = lane & 15;

    const int flat  = blockIdx.x;
    const int combo = flat & 31;
    const int batch = combo >> 3;
    const int jh    = combo & 7;
    const int iblk  = flat >> 5;
    const int iw    = iblk * IPB + w * IPW;
    const size_t rowbase = (size_t)batch * N_TOK;

    const float tau    = temp[0];
    const float inv2t2 = 0.5f / (tau * tau);
    const float cg     = 1.0f / (tau * tau);

    // A fragments: 4 strips x 16 k-chunks x 8B = 128 regs
    long afrag[4][16];
#pragma unroll
    for (int s = 0; s < 4; ++s) {
        const long* ap = (const long*)(fb + (rowbase + iw + s * 16 + c16) * DIM);
#pragma unroll
        for (int kc = 0; kc < 16; ++kc) afrag[s][kc] = ap[kc * 4 + q];
    }
    float pi[4][4];
#pragma unroll
    for (int s = 0; s < 4; ++s)
#pragma unroll
        for (int r = 0; r < 4; ++r)
            pi[s][r] = -sq[rowbase + iw + s * 16 + q * 4 + r] * inv2t2;

    float S[4][4], T[4][4];
#pragma unroll
    for (int s = 0; s < 4; ++s)
#pragma unroll
        for (int r = 0; r < 4; ++r) { S[s][r] = 0.f; T[s][r] = 0.f; }

    // per-lane B pointer: 16B units; group stride 512 units, kp stride 64 units
    const longlong2* bp = (const longlong2*)(fbT
                        + ((size_t)batch * (N_TOK / 16) + (size_t)jh * NG) * 8192) + lane;
    const float* sqj = sq + rowbase + jh * (N_TOK / JSPLIT) + c16;

    for (int g = 0; g < NG; ++g) {
        float pj = -sqj[g * 16] * inv2t2;
        const longlong2* bg = bp + (size_t)g * 512;
        f32x4 acc[4] = {{0,0,0,0},{0,0,0,0},{0,0,0,0},{0,0,0,0}};
#pragma unroll
        for (int kp = 0; kp < 8; ++kp) {
            longlong2 v = bg[kp * 64];             // coalesced 1KB wave load, 2 kc
            acc[0] = __builtin_amdgcn_mfma_f32_16x16x32_fp8_fp8(afrag[0][2*kp],   v.x, acc[0], 0, 0, 0);
            acc[1] = __builtin_amdgcn_mfma_f32_16x16x32_fp8_fp8(afrag[1][2*kp],   v.x, acc[1], 0, 0, 0);
            acc[2] = __builtin_amdgcn_mfma_f32_16x16x32_fp8_fp8(afrag[2][2*kp],   v.x, acc[2], 0, 0, 0);
            acc[3] = __builtin_amdgcn_mfma_f32_16x16x32_fp8_fp8(afrag[3][2*kp],   v.x, acc[3], 0, 0, 0);
            acc[0] = __builtin_amdgcn_mfma_f32_16x16x32_fp8_fp8(afrag[0][2*kp+1], v.y, acc[0], 0, 0, 0);
            acc[1] = __builtin_amdgcn_mfma_f32_16x16x32_fp8_fp8(afrag[1][2*kp+1], v.y, acc[1], 0, 0, 0);
            acc[2] = __builtin_amdgcn_mfma_f32_16x16x32_fp8_fp8(afrag[2][2*kp+1], v.y, acc[2], 0, 0, 0);
            acc[3] = __builtin_amdgcn_mfma_f32_16x16x32_fp8_fp8(afrag[3][2*kp+1], v.y, acc[3], 0, 0, 0);
        }
        float m = -1e30f;
#pragma unroll
        for (int s = 0; s < 4; ++s)
#pragma unroll
            for (int r = 0; r < 4; ++r) {          // e in place of acc (dead after)
                acc[s][r] = fmaf(acc[s][r], cg, pi[s][r] + pj);
                m = fmaxf(m, acc[s][r]);
            }
        if (m > -110.0f) {                         // only diagonal-adjacent groups
#pragma unroll
            for (int s = 0; s < 4; ++s)
#pragma unroll
                for (int r = 0; r < 4; ++r) {
                    float ee = fminf(acc[s][r], 0.f);
                    float k  = __expf(ee);
                    S[s][r] += k;
                    T[s][r]  = fmaf(k, ee, T[s][r]);
                }
        }
    }

    // reduce over the 16 j-columns (c16 lanes)
#pragma unroll
    for (int m = 1; m < 16; m <<= 1)
#pragma unroll
        for (int s = 0; s < 4; ++s)
#pragma unroll
            for (int r = 0; r < 4; ++r) {
                S[s][r] += __shfl_xor(S[s][r], m);
                T[s][r] += __shfl_xor(T[s][r], m);
            }

    if (c16 == 0) {
#pragma unroll
        for (int s = 0; s < 4; ++s)
#pragma unroll
            for (int r = 0; r < 4; ++r) {
                size_t idx = (size_t)jh * BN + rowbase + iw + s * 16 + q * 4 + r;
                Sp[idx] = S[s][r];
                Tp[idx] = T[s][r];
            }
    }
}

// ---------- finalize: combine partials, entropy -> sigmoid -> scale features ----------
__global__ __launch_bounds__(256) void finalize_kernel(
    const float* __restrict__ feat, const float* __restrict__ Sp,
    const float* __restrict__ Tp, const float* __restrict__ tgt,
    const float* __restrict__ temp, float* __restrict__ out)
{
    int row  = (blockIdx.x << 2) + (threadIdx.x >> 6);   // global row 0..BN-1
    int lane = threadIdx.x & 63;
    float S = 0.0f, T = 0.0f;
#pragma unroll
    for (int j = 0; j < JSPLIT; ++j) {
        S += Sp[(size_t)j * BN + row];
        T += Tp[(size_t)j * BN + row];
    }
    float tau = temp[0];
    float E  = __logf(S) - T / S;                  // entropy (sans +1e-6, bias<4e-3)
    float cs = 1.0f / (1.0f + __expf((E - tgt[0]) / tau));

    const float4* F4 = (const float4*)(feat + (size_t)row * DIM);
    float4*       O4 = (float4*)(out + (size_t)row * DIM);
    float4 v0 = F4[lane], v1 = F4[lane + 64];
    v0.x *= cs; v0.y *= cs; v0.z *= cs; v0.w *= cs;
    v1.x *= cs; v1.y *= cs; v1.z *= cs; v1.w *= cs;
    O4[lane] = v0; O4[lane + 64] = v1;
    if (lane == 0) out[(size_t)BN * DIM + row] = cs;
}

extern "C" void kernel_launch(void* const* d_in, const int* in_sizes, int n_in,
                              void* d_out, int out_size, void* d_ws, size_t ws_size,
                              hipStream_t stream) {
    const float* feat = (const float*)d_in[0];
    const float* tgt  = (const float*)d_in[7];   // target_entropy
    const float* temp = (const float*)d_in[8];   // temperature
    float* out = (float*)d_out;

    char* ws = (char*)d_ws;
    uint8_t* fb  = (uint8_t*)ws;                               // fp8 row-major, 8.4MB
    uint8_t* fbT = fb + (size_t)BN * DIM;                      // fp8 B-layout, 8.4MB
    float*   sq  = (float*)(fbT + (size_t)BN * DIM);           // quantized row sumsq
    float*   Sp  = sq + BN;                                    // partial S, JSPLIT slices
    float*   Tp  = Sp + (size_t)JSPLIT * BN;                   // partial T, JSPLIT slices

    prep_kernel<<<dim3(BN / 16), dim3(256), 0, stream>>>(feat, fb, fbT, sq);
    entropy_kernel<<<dim3((N_TOK / IPB) * BATCH * JSPLIT), dim3(256), 0, stream>>>(fb, fbT, sq, temp, Sp, Tp);
    finalize_kernel<<<dim3(BN / 4), dim3(256), 0, stream>>>(feat, Sp, Tp, tgt, temp, out);
}